// Round 1
// baseline (4383.857 us; speedup 1.0000x reference)
//
#include <hip/hip_runtime.h>

#define ALPHA 0.2f

static __device__ __forceinline__ float leaky_f(float v) {
  return v >= 0.0f ? v : ALPHA * v;
}

__global__ __launch_bounds__(256) void copy_f4_kernel(const float4* __restrict__ in,
                                                      float4* __restrict__ out, int n4) {
  int i = blockIdx.x * blockDim.x + threadIdx.x;
  if (i < n4) out[i] = in[i];
}

// For each edge e: agg[dst[e]][:] += x[src[e]][:]   (F = 4*F4 features)
template <int F4>
__global__ __launch_bounds__(256) void scatter_add_kernel(const float* __restrict__ x,
                                                          const int* __restrict__ src,
                                                          const int* __restrict__ dst,
                                                          float* __restrict__ agg, int total) {
  int id = blockIdx.x * blockDim.x + threadIdx.x;
  if (id >= total) return;
  int e = id / F4;           // F4 is power of two -> shift
  int j = id - e * F4;
  int s = src[e];
  int d = dst[e];
  float4 v = reinterpret_cast<const float4*>(x)[s * F4 + j];
  float* o = agg + ((long long)d * F4 + j) * 4;
  atomicAdd(o + 0, v.x);
  atomicAdd(o + 1, v.y);
  atomicAdd(o + 2, v.z);
  atomicAdd(o + 3, v.w);
}

// C[M,N] = leaky(A[M,K] @ W[K,N] + bias[N]); row-major everywhere.
// BM=64, BN=64, BK=32, 256 threads, 4x4 micro-tile per thread.
template <int BM, int BN, int BK>
__global__ __launch_bounds__(256) void gemm_bias_leaky(const float* __restrict__ A,
                                                       const float* __restrict__ W,
                                                       const float* __restrict__ bias,
                                                       float* __restrict__ C,
                                                       int M, int N, int K) {
  __shared__ float As[BM][BK + 1];     // +1 pad: A-reads conflict-free
  __shared__ float Bs[BK][BN + 4];     // +4 pad: keeps float4 alignment, 2-way (free)
  const int tid = threadIdx.x;
  const int tx = tid & 15;
  const int ty = tid >> 4;
  const int bm = blockIdx.x * BM;
  const int bn = blockIdx.y * BN;

  float acc[4][4] = {};

  for (int k0 = 0; k0 < K; k0 += BK) {
    // --- stage A tile (BM x BK) ---
    constexpr int AF4 = BK / 4;                 // float4 per A row
    #pragma unroll
    for (int i = tid; i < BM * BK / 4; i += 256) {
      int row = i / AF4;
      int c4 = i - row * AF4;
      float4 v = make_float4(0.f, 0.f, 0.f, 0.f);
      if (bm + row < M)
        v = reinterpret_cast<const float4*>(A + (long long)(bm + row) * K + k0)[c4];
      As[row][c4 * 4 + 0] = v.x;
      As[row][c4 * 4 + 1] = v.y;
      As[row][c4 * 4 + 2] = v.z;
      As[row][c4 * 4 + 3] = v.w;
    }
    // --- stage B tile (BK x BN); N,K multiples of tile so no guard ---
    constexpr int BF4 = BN / 4;
    #pragma unroll
    for (int i = tid; i < BK * BN / 4; i += 256) {
      int row = i / BF4;
      int c4 = i - row * BF4;
      float4 v = reinterpret_cast<const float4*>(W + (long long)(k0 + row) * N + bn)[c4];
      *reinterpret_cast<float4*>(&Bs[row][c4 * 4]) = v;
    }
    __syncthreads();

    #pragma unroll
    for (int k = 0; k < BK; ++k) {
      float a0 = As[ty * 4 + 0][k];
      float a1 = As[ty * 4 + 1][k];
      float a2 = As[ty * 4 + 2][k];
      float a3 = As[ty * 4 + 3][k];
      float4 b = *reinterpret_cast<const float4*>(&Bs[k][tx * 4]);
      acc[0][0] += a0 * b.x; acc[0][1] += a0 * b.y; acc[0][2] += a0 * b.z; acc[0][3] += a0 * b.w;
      acc[1][0] += a1 * b.x; acc[1][1] += a1 * b.y; acc[1][2] += a1 * b.z; acc[1][3] += a1 * b.w;
      acc[2][0] += a2 * b.x; acc[2][1] += a2 * b.y; acc[2][2] += a2 * b.z; acc[2][3] += a2 * b.w;
      acc[3][0] += a3 * b.x; acc[3][1] += a3 * b.y; acc[3][2] += a3 * b.z; acc[3][3] += a3 * b.w;
    }
    __syncthreads();
  }

  float4 bv = *reinterpret_cast<const float4*>(&bias[bn + tx * 4]);
  #pragma unroll
  for (int i = 0; i < 4; ++i) {
    int row = bm + ty * 4 + i;
    if (row < M) {
      float4 o;
      o.x = leaky_f(acc[i][0] + bv.x);
      o.y = leaky_f(acc[i][1] + bv.y);
      o.z = leaky_f(acc[i][2] + bv.z);
      o.w = leaky_f(acc[i][3] + bv.w);
      *reinterpret_cast<float4*>(&C[(long long)row * N + bn + tx * 4]) = o;
    }
  }
}

// out[m] = dot(h[m,:128], w5) + b5  -- one wave per row
__global__ __launch_bounds__(256) void final_dot_kernel(const float* __restrict__ h,
                                                        const float* __restrict__ w,
                                                        const float* __restrict__ b,
                                                        float* __restrict__ out, int M) {
  int gw = (blockIdx.x * blockDim.x + threadIdx.x) >> 6;  // wave id == row
  int lane = threadIdx.x & 63;
  if (gw >= M) return;
  const float* hr = h + (long long)gw * 128;
  float s = hr[lane] * w[lane] + hr[lane + 64] * w[lane + 64];
  #pragma unroll
  for (int off = 32; off; off >>= 1) s += __shfl_down(s, off, 64);
  if (lane == 0) out[gw] = s + b[0];
}

extern "C" void kernel_launch(void* const* d_in, const int* in_sizes, int n_in,
                              void* d_out, int out_size, void* d_ws, size_t ws_size,
                              hipStream_t stream) {
  const float* x  = (const float*)d_in[0];
  const int*   ei = (const int*)d_in[2];
  const float* W1 = (const float*)d_in[3];
  const float* b1 = (const float*)d_in[4];
  const float* W2 = (const float*)d_in[5];
  const float* b2 = (const float*)d_in[6];
  const float* W3 = (const float*)d_in[7];
  const float* b3 = (const float*)d_in[8];
  const float* W4 = (const float*)d_in[9];
  const float* b4 = (const float*)d_in[10];
  const float* W5 = (const float*)d_in[11];
  const float* b5 = (const float*)d_in[12];
  float* out = (float*)d_out;

  const int M = in_sizes[0] / 128;  // 50000 nodes
  const int E = in_sizes[2] / 2;    // 800000 edges
  const int* src = ei;
  const int* dst = ei + E;

  float* B0 = (float*)d_ws;
  float* B1 = B0 + (size_t)M * 256;

  dim3 blk(256);

  // 1) agg1 = x  (B0[:, :128])
  {
    int n4 = M * 128 / 4;
    copy_f4_kernel<<<(n4 + 255) / 256, blk, 0, stream>>>((const float4*)x, (float4*)B0, n4);
  }
  // 2) agg1[dst] += x[src]
  {
    int total = E * 32;
    scatter_add_kernel<32><<<(total + 255) / 256, blk, 0, stream>>>(x, src, dst, B0, total);
  }
  // 3) B1 = leaky(B0 @ W1 + b1)   [M,128]@[128,256]
  {
    dim3 g((M + 63) / 64, 256 / 64);
    gemm_bias_leaky<64, 64, 32><<<g, blk, 0, stream>>>(B0, W1, b1, B1, M, 256, 128);
  }
  // 4) B0 = leaky(B1 @ W2 + b2)   [M,256]@[256,256]   (= h1)
  {
    dim3 g((M + 63) / 64, 256 / 64);
    gemm_bias_leaky<64, 64, 32><<<g, blk, 0, stream>>>(B1, W2, b2, B0, M, 256, 256);
  }
  // 5) agg2 = h1  (B1 = B0)
  {
    int n4 = M * 256 / 4;
    copy_f4_kernel<<<(n4 + 255) / 256, blk, 0, stream>>>((const float4*)B0, (float4*)B1, n4);
  }
  // 6) agg2[dst] += h1[src]
  {
    int total = E * 64;
    scatter_add_kernel<64><<<(total + 255) / 256, blk, 0, stream>>>(B0, src, dst, B1, total);
  }
  // 7) B0 = leaky(B1 @ W3 + b3)   [M,256]@[256,256]
  {
    dim3 g((M + 63) / 64, 256 / 64);
    gemm_bias_leaky<64, 64, 32><<<g, blk, 0, stream>>>(B1, W3, b3, B0, M, 256, 256);
  }
  // 8) B1 = leaky(B0 @ W4 + b4)   [M,256]@[256,128]   (= h2)
  {
    dim3 g((M + 63) / 64, 128 / 64);
    gemm_bias_leaky<64, 64, 32><<<g, blk, 0, stream>>>(B0, W4, b4, B1, M, 128, 256);
  }
  // 9) out = B1 @ W5 + b5
  final_dot_kernel<<<(M + 3) / 4, blk, 0, stream>>>(B1, W5, b5, out, M);
}

// Round 2
// 729.739 us; speedup vs baseline: 6.0074x; 6.0074x over previous
//
#include <hip/hip_runtime.h>

#define ALPHA 0.2f

static __device__ __forceinline__ float leaky_f(float v) {
  return v >= 0.0f ? v : ALPHA * v;
}

// ---------- CSR build ----------

__global__ __launch_bounds__(256) void zero_int_kernel(int* __restrict__ p, int n) {
  int i = blockIdx.x * blockDim.x + threadIdx.x;
  if (i < n) p[i] = 0;
}

__global__ __launch_bounds__(256) void hist_kernel(const int* __restrict__ dst,
                                                   int* __restrict__ cnt, int E) {
  int e = blockIdx.x * blockDim.x + threadIdx.x;
  if (e < E) atomicAdd(&cnt[dst[e]], 1);
}

// cursor holds degrees on entry; on exit off[] = exclusive scan (n+1 entries),
// cursor[] = same exclusive scan (to be used as fill cursors).
__global__ __launch_bounds__(1024) void scan_kernel(int* __restrict__ cursor,
                                                    int* __restrict__ off, int n) {
  __shared__ int sums[1024];
  int t = threadIdx.x;
  int chunk = (n + 1023) >> 10;
  int lo = min(t * chunk, n), hi = min(lo + chunk, n);
  int s = 0;
  for (int i = lo; i < hi; ++i) s += cursor[i];
  sums[t] = s;
  __syncthreads();
  for (int d = 1; d < 1024; d <<= 1) {
    int v = (t >= d) ? sums[t - d] : 0;
    __syncthreads();
    sums[t] += v;
    __syncthreads();
  }
  if (t == 0) off[n] = sums[1023];
  int run = (t == 0) ? 0 : sums[t - 1];
  for (int i = lo; i < hi; ++i) {
    int d = cursor[i];
    off[i] = run;
    cursor[i] = run;
    run += d;
  }
}

__global__ __launch_bounds__(256) void fill_kernel(const int* __restrict__ src,
                                                   const int* __restrict__ dst,
                                                   int* __restrict__ cursor,
                                                   int* __restrict__ csr, int E) {
  int e = blockIdx.x * blockDim.x + threadIdx.x;
  if (e < E) {
    int p = atomicAdd(&cursor[dst[e]], 1);
    csr[p] = src[e];
  }
}

// ---------- aggregation: agg[i] = x[i] + sum_{p} x[csr[p]] ----------
template <int F4>  // float4 lanes per node: 32 (F=128) or 64 (F=256)
__global__ __launch_bounds__(256) void gather_agg(const float* __restrict__ x,
                                                  const int* __restrict__ off,
                                                  const int* __restrict__ csr,
                                                  float* __restrict__ agg, int M) {
  constexpr int GP = 256 / F4;
  int g = threadIdx.x / F4;
  int lane = threadIdx.x % F4;
  int node = blockIdx.x * GP + g;
  if (node >= M) return;
  const float4* xv = reinterpret_cast<const float4*>(x);
  float4 acc = xv[(size_t)node * F4 + lane];
  int p0 = off[node], p1 = off[node + 1];
  for (int p = p0; p < p1; ++p) {
    int s = csr[p];  // uniform within group -> broadcast
    float4 v = xv[(size_t)s * F4 + lane];
    acc.x += v.x; acc.y += v.y; acc.z += v.z; acc.w += v.w;
  }
  reinterpret_cast<float4*>(agg)[(size_t)node * F4 + lane] = acc;
}

// ---------- GEMM: C = leaky(A @ W + bias), row-major ----------
// BM=BN=128, BK=16, 256 threads, 8x8 microtile (2x2 blocks of 4x4).
template <int BM, int BN, int BK>
__global__ __launch_bounds__(256) void gemm_bias_leaky(const float* __restrict__ A,
                                                       const float* __restrict__ W,
                                                       const float* __restrict__ bias,
                                                       float* __restrict__ C,
                                                       int M, int N, int K) {
  __shared__ float As[BK][BM + 1];   // transposed A tile
  __shared__ float Bs[BK][BN + 4];
  const int tid = threadIdx.x;
  const int tx = tid & 15;           // col group 0..15
  const int ty = tid >> 4;           // row group 0..15
  const int bm = blockIdx.x * BM;
  const int bn = blockIdx.y * BN;

  float acc[8][8] = {};

  for (int k0 = 0; k0 < K; k0 += BK) {
    // stage A (BM x BK) transposed: As[k][m]
    #pragma unroll
    for (int i = tid; i < BM * BK / 4; i += 256) {
      int row = i >> 2;              // BK/4 = 4 float4 per row
      int c4 = i & 3;
      float4 v = make_float4(0.f, 0.f, 0.f, 0.f);
      if (bm + row < M)
        v = reinterpret_cast<const float4*>(A + (size_t)(bm + row) * K + k0)[c4];
      As[c4 * 4 + 0][row] = v.x;
      As[c4 * 4 + 1][row] = v.y;
      As[c4 * 4 + 2][row] = v.z;
      As[c4 * 4 + 3][row] = v.w;
    }
    // stage B (BK x BN) direct
    #pragma unroll
    for (int i = tid; i < BK * BN / 4; i += 256) {
      int row = i >> 5;              // BN/4 = 32 float4 per row
      int c4 = i & 31;
      float4 v = reinterpret_cast<const float4*>(W + (size_t)(k0 + row) * N + bn)[c4];
      *reinterpret_cast<float4*>(&Bs[row][c4 * 4]) = v;
    }
    __syncthreads();

    #pragma unroll
    for (int k = 0; k < BK; ++k) {
      float4 a0 = *reinterpret_cast<const float4*>(&As[k][ty * 4]);
      float4 a1 = *reinterpret_cast<const float4*>(&As[k][64 + ty * 4]);
      float4 b0 = *reinterpret_cast<const float4*>(&Bs[k][tx * 4]);
      float4 b1 = *reinterpret_cast<const float4*>(&Bs[k][64 + tx * 4]);
      float a[8] = {a0.x, a0.y, a0.z, a0.w, a1.x, a1.y, a1.z, a1.w};
      float b[8] = {b0.x, b0.y, b0.z, b0.w, b1.x, b1.y, b1.z, b1.w};
      #pragma unroll
      for (int r = 0; r < 8; ++r)
        #pragma unroll
        for (int c = 0; c < 8; ++c)
          acc[r][c] += a[r] * b[c];
    }
    __syncthreads();
  }

  float4 bv0 = *reinterpret_cast<const float4*>(&bias[bn + tx * 4]);
  float4 bv1 = *reinterpret_cast<const float4*>(&bias[bn + 64 + tx * 4]);
  float bvf[8] = {bv0.x, bv0.y, bv0.z, bv0.w, bv1.x, bv1.y, bv1.z, bv1.w};
  #pragma unroll
  for (int r = 0; r < 8; ++r) {
    int grow = bm + (r < 4 ? ty * 4 + r : 64 + ty * 4 + (r - 4));
    if (grow < M) {
      float4 o0, o1;
      o0.x = leaky_f(acc[r][0] + bvf[0]);
      o0.y = leaky_f(acc[r][1] + bvf[1]);
      o0.z = leaky_f(acc[r][2] + bvf[2]);
      o0.w = leaky_f(acc[r][3] + bvf[3]);
      o1.x = leaky_f(acc[r][4] + bvf[4]);
      o1.y = leaky_f(acc[r][5] + bvf[5]);
      o1.z = leaky_f(acc[r][6] + bvf[6]);
      o1.w = leaky_f(acc[r][7] + bvf[7]);
      *reinterpret_cast<float4*>(&C[(size_t)grow * N + bn + tx * 4]) = o0;
      *reinterpret_cast<float4*>(&C[(size_t)grow * N + bn + 64 + tx * 4]) = o1;
    }
  }
}

// out[m] = dot(h[m,:128], w5) + b5 -- one wave per row
__global__ __launch_bounds__(256) void final_dot_kernel(const float* __restrict__ h,
                                                        const float* __restrict__ w,
                                                        const float* __restrict__ b,
                                                        float* __restrict__ out, int M) {
  int gw = (blockIdx.x * blockDim.x + threadIdx.x) >> 6;
  int lane = threadIdx.x & 63;
  if (gw >= M) return;
  const float* hr = h + (size_t)gw * 128;
  float s = hr[lane] * w[lane] + hr[lane + 64] * w[lane + 64];
  #pragma unroll
  for (int off = 32; off; off >>= 1) s += __shfl_down(s, off, 64);
  if (lane == 0) out[gw] = s + b[0];
}

extern "C" void kernel_launch(void* const* d_in, const int* in_sizes, int n_in,
                              void* d_out, int out_size, void* d_ws, size_t ws_size,
                              hipStream_t stream) {
  const float* x  = (const float*)d_in[0];
  const int*   ei = (const int*)d_in[2];
  const float* W1 = (const float*)d_in[3];
  const float* b1 = (const float*)d_in[4];
  const float* W2 = (const float*)d_in[5];
  const float* b2 = (const float*)d_in[6];
  const float* W3 = (const float*)d_in[7];
  const float* b3 = (const float*)d_in[8];
  const float* W4 = (const float*)d_in[9];
  const float* b4 = (const float*)d_in[10];
  const float* W5 = (const float*)d_in[11];
  const float* b5 = (const float*)d_in[12];
  float* out = (float*)d_out;

  const int M = in_sizes[0] / 128;  // 50000 nodes
  const int E = in_sizes[2] / 2;    // 800000 edges
  const int* src = ei;
  const int* dst = ei + E;

  // workspace layout
  float* B0 = (float*)d_ws;                 // M*256 floats
  float* B1 = B0 + (size_t)M * 256;         // M*256 floats
  int* off    = (int*)(B1 + (size_t)M * 256);  // M+1
  int* cursor = off + (M + 1);                 // M
  int* csr    = cursor + M;                    // E

  dim3 blk(256);

  // ---- CSR build ----
  zero_int_kernel<<<(M + 255) / 256, blk, 0, stream>>>(cursor, M);
  hist_kernel<<<(E + 255) / 256, blk, 0, stream>>>(dst, cursor, E);
  scan_kernel<<<1, 1024, 0, stream>>>(cursor, off, M);
  fill_kernel<<<(E + 255) / 256, blk, 0, stream>>>(src, dst, cursor, csr, E);

  // ---- layer 1 ----
  gather_agg<32><<<(M + 7) / 8, blk, 0, stream>>>(x, off, csr, B0, M);
  {
    dim3 g((M + 127) / 128, 256 / 128);
    gemm_bias_leaky<128, 128, 16><<<g, blk, 0, stream>>>(B0, W1, b1, B1, M, 256, 128);
    gemm_bias_leaky<128, 128, 16><<<g, blk, 0, stream>>>(B1, W2, b2, B0, M, 256, 256);
  }
  // ---- layer 2 ----
  gather_agg<64><<<(M + 3) / 4, blk, 0, stream>>>(B0, off, csr, B1, M);
  {
    dim3 g((M + 127) / 128, 256 / 128);
    gemm_bias_leaky<128, 128, 16><<<g, blk, 0, stream>>>(B1, W3, b3, B0, M, 256, 256);
    dim3 g2((M + 127) / 128, 128 / 128);
    gemm_bias_leaky<128, 128, 16><<<g2, blk, 0, stream>>>(B0, W4, b4, B1, M, 128, 256);
  }
  // ---- final linear ----
  final_dot_kernel<<<(M + 3) / 4, blk, 0, stream>>>(B1, W5, b5, out, M);
}

// Round 3
// 551.164 us; speedup vs baseline: 7.9538x; 1.3240x over previous
//
#include <hip/hip_runtime.h>

#define ALPHA 0.2f

typedef __attribute__((ext_vector_type(8))) short bf16x8;
typedef __attribute__((ext_vector_type(4))) float f32x4;

static __device__ __forceinline__ float leaky_f(float v) {
  return v >= 0.0f ? v : ALPHA * v;
}

static __device__ __forceinline__ unsigned short f2bf(float f) {
  unsigned u = __float_as_uint(f);
  unsigned r = (u + 0x7FFFu + ((u >> 16) & 1u)) >> 16;
  return (unsigned short)r;
}
static __device__ __forceinline__ float bf2f(unsigned short h) {
  return __uint_as_float(((unsigned)h) << 16);
}

// ---------- CSR build ----------

__global__ __launch_bounds__(256) void zero_int_kernel(int* __restrict__ p, int n) {
  int i = blockIdx.x * blockDim.x + threadIdx.x;
  if (i < n) p[i] = 0;
}

__global__ __launch_bounds__(256) void hist_kernel(const int* __restrict__ dst,
                                                   int* __restrict__ cnt, int E) {
  int e = blockIdx.x * blockDim.x + threadIdx.x;
  if (e < E) atomicAdd(&cnt[dst[e]], 1);
}

__global__ __launch_bounds__(1024) void scan_kernel(int* __restrict__ cursor,
                                                    int* __restrict__ off, int n) {
  __shared__ int sums[1024];
  int t = threadIdx.x;
  int chunk = (n + 1023) >> 10;
  int lo = min(t * chunk, n), hi = min(lo + chunk, n);
  int s = 0;
  for (int i = lo; i < hi; ++i) s += cursor[i];
  sums[t] = s;
  __syncthreads();
  for (int d = 1; d < 1024; d <<= 1) {
    int v = (t >= d) ? sums[t - d] : 0;
    __syncthreads();
    sums[t] += v;
    __syncthreads();
  }
  if (t == 0) off[n] = sums[1023];
  int run = (t == 0) ? 0 : sums[t - 1];
  for (int i = lo; i < hi; ++i) {
    int d = cursor[i];
    off[i] = run;
    cursor[i] = run;
    run += d;
  }
}

__global__ __launch_bounds__(256) void fill_kernel(const int* __restrict__ src,
                                                   const int* __restrict__ dst,
                                                   int* __restrict__ cursor,
                                                   int* __restrict__ csr, int E) {
  int e = blockIdx.x * blockDim.x + threadIdx.x;
  if (e < E) {
    int p = atomicAdd(&cursor[dst[e]], 1);
    csr[p] = src[e];
  }
}

// ---------- aggregation: agg[i] = x[i] + sum_{p} x[csr[p]] ----------
template <int F4>
__global__ __launch_bounds__(256) void gather_agg(const float* __restrict__ x,
                                                  const int* __restrict__ off,
                                                  const int* __restrict__ csr,
                                                  float* __restrict__ agg, int M) {
  constexpr int GP = 256 / F4;
  int g = threadIdx.x / F4;
  int lane = threadIdx.x % F4;
  int node = blockIdx.x * GP + g;
  if (node >= M) return;
  const float4* xv = reinterpret_cast<const float4*>(x);
  float4 acc = xv[(size_t)node * F4 + lane];
  int p0 = off[node], p1 = off[node + 1];
  for (int p = p0; p < p1; ++p) {
    int s = csr[p];
    float4 v = xv[(size_t)s * F4 + lane];
    acc.x += v.x; acc.y += v.y; acc.z += v.z; acc.w += v.w;
  }
  reinterpret_cast<float4*>(agg)[(size_t)node * F4 + lane] = acc;
}

// ---------- weight prep: W [K][N] f32 -> Wh, Wl [N][K] bf16 (hi/lo split) ----------
__global__ __launch_bounds__(256) void prep_w(const float* __restrict__ W,
                                              unsigned short* __restrict__ Wh,
                                              unsigned short* __restrict__ Wl,
                                              int K, int N) {
  __shared__ float T[32][65];
  int k0 = blockIdx.x * 32, n0 = blockIdx.y * 64;
  int t = threadIdx.x;
  int nn = t & 63, kk0 = t >> 6;
  #pragma unroll
  for (int i = 0; i < 8; ++i) {
    int kk = kk0 + i * 4;
    T[kk][nn] = W[(size_t)(k0 + kk) * N + n0 + nn];
  }
  __syncthreads();
  int kk = t & 31, nb = t >> 5;
  #pragma unroll
  for (int i = 0; i < 8; ++i) {
    int n2 = nb + i * 8;
    float f = T[kk][n2];
    unsigned short h = f2bf(f);
    float r = f - bf2f(h);
    Wh[(size_t)(n0 + n2) * K + k0 + kk] = h;
    Wl[(size_t)(n0 + n2) * K + k0 + kk] = f2bf(r);
  }
}

// ---------- GEMM: C = leaky(A @ W + bias) via 3-product bf16-split MFMA ----------
// A [M][K] f32 row-major; Bh/Bl [N][K] bf16 row-major (pre-transposed W).
// Block 128x128, BK=32, 4 waves each computing 64x64.
__global__ __launch_bounds__(256, 3) void gemm_mfma(const float* __restrict__ A,
                                                    const unsigned short* __restrict__ Bh,
                                                    const unsigned short* __restrict__ Bl,
                                                    const float* __restrict__ bias,
                                                    float* __restrict__ C,
                                                    int M, int N, int K) {
  __shared__ unsigned short Ah_s[128 * 32];
  __shared__ unsigned short Al_s[128 * 32];
  __shared__ unsigned short Bh_s[128 * 32];
  __shared__ unsigned short Bl_s[128 * 32];

  const int tid = threadIdx.x;
  const int bm = blockIdx.x * 128, bn = blockIdx.y * 128;
  const int lane = tid & 63;
  const int wave = tid >> 6;
  const int wr = (wave >> 1) * 64;   // wave row offset in tile
  const int wc = (wave & 1) * 64;    // wave col offset in tile

  f32x4 acc[4][4];
  #pragma unroll
  for (int mi = 0; mi < 4; ++mi)
    #pragma unroll
    for (int ni = 0; ni < 4; ++ni)
      acc[mi][ni] = (f32x4){0.f, 0.f, 0.f, 0.f};

  const int lrow = lane & 15;
  const int lslot = lane >> 4;

  for (int k0 = 0; k0 < K; k0 += 32) {
    // --- stage A: fp32 -> split hi/lo bf16, swizzled ---
    #pragma unroll
    for (int h = 0; h < 2; ++h) {
      int p = tid + h * 256;            // 512 (row,slot) pairs
      int row = p >> 2, slot = p & 3;
      const float4* srcp =
          reinterpret_cast<const float4*>(A + (size_t)(bm + row) * K + k0 + slot * 8);
      float4 v0 = srcp[0], v1 = srcp[1];
      float vs[8] = {v0.x, v0.y, v0.z, v0.w, v1.x, v1.y, v1.z, v1.w};
      uint4 uh, ul;
      unsigned uhw[4], ulw[4];
      #pragma unroll
      for (int q = 0; q < 4; ++q) {
        unsigned short h0 = f2bf(vs[2 * q]);
        unsigned short h1 = f2bf(vs[2 * q + 1]);
        unsigned short l0 = f2bf(vs[2 * q] - bf2f(h0));
        unsigned short l1 = f2bf(vs[2 * q + 1] - bf2f(h1));
        uhw[q] = (unsigned)h0 | ((unsigned)h1 << 16);
        ulw[q] = (unsigned)l0 | ((unsigned)l1 << 16);
      }
      uh.x = uhw[0]; uh.y = uhw[1]; uh.z = uhw[2]; uh.w = uhw[3];
      ul.x = ulw[0]; ul.y = ulw[1]; ul.z = ulw[2]; ul.w = ulw[3];
      int dst = row * 32 + ((slot ^ ((row >> 1) & 3)) << 3);
      *reinterpret_cast<uint4*>(&Ah_s[dst]) = uh;
      *reinterpret_cast<uint4*>(&Al_s[dst]) = ul;
    }
    // --- stage B: bf16 copy, swizzled ---
    #pragma unroll
    for (int h = 0; h < 2; ++h) {
      int p = tid + h * 256;
      int row = p >> 2, slot = p & 3;
      int dst = row * 32 + ((slot ^ ((row >> 1) & 3)) << 3);
      uint4 vh = *reinterpret_cast<const uint4*>(Bh + (size_t)(bn + row) * K + k0 + slot * 8);
      uint4 vl = *reinterpret_cast<const uint4*>(Bl + (size_t)(bn + row) * K + k0 + slot * 8);
      *reinterpret_cast<uint4*>(&Bh_s[dst]) = vh;
      *reinterpret_cast<uint4*>(&Bl_s[dst]) = vl;
    }
    __syncthreads();

    // --- fragments + MFMA ---
    bf16x8 ah[4], al[4], bh[4], bl[4];
    #pragma unroll
    for (int mi = 0; mi < 4; ++mi) {
      int r = wr + mi * 16 + lrow;
      int off = r * 32 + (((lslot ^ ((r >> 1) & 3))) << 3);
      ah[mi] = *reinterpret_cast<const bf16x8*>(&Ah_s[off]);
      al[mi] = *reinterpret_cast<const bf16x8*>(&Al_s[off]);
    }
    #pragma unroll
    for (int ni = 0; ni < 4; ++ni) {
      int r = wc + ni * 16 + lrow;
      int off = r * 32 + (((lslot ^ ((r >> 1) & 3))) << 3);
      bh[ni] = *reinterpret_cast<const bf16x8*>(&Bh_s[off]);
      bl[ni] = *reinterpret_cast<const bf16x8*>(&Bl_s[off]);
    }
    #pragma unroll
    for (int mi = 0; mi < 4; ++mi)
      #pragma unroll
      for (int ni = 0; ni < 4; ++ni) {
        acc[mi][ni] = __builtin_amdgcn_mfma_f32_16x16x32_bf16(ah[mi], bh[ni], acc[mi][ni], 0, 0, 0);
        acc[mi][ni] = __builtin_amdgcn_mfma_f32_16x16x32_bf16(ah[mi], bl[ni], acc[mi][ni], 0, 0, 0);
        acc[mi][ni] = __builtin_amdgcn_mfma_f32_16x16x32_bf16(al[mi], bh[ni], acc[mi][ni], 0, 0, 0);
      }
    __syncthreads();
  }

  // --- epilogue: bias + leaky, C layout col=lane&15, row=(lane>>4)*4+j ---
  #pragma unroll
  for (int ni = 0; ni < 4; ++ni) {
    int col = bn + wc + ni * 16 + lrow;
    float bv = bias[col];
    #pragma unroll
    for (int mi = 0; mi < 4; ++mi) {
      int rbase = bm + wr + mi * 16 + lslot * 4;
      #pragma unroll
      for (int j = 0; j < 4; ++j) {
        int row = rbase + j;
        if (row < M) C[(size_t)row * N + col] = leaky_f(acc[mi][ni][j] + bv);
      }
    }
  }
}

// out[m] = dot(h[m,:128], w5) + b5 -- one wave per row
__global__ __launch_bounds__(256) void final_dot_kernel(const float* __restrict__ h,
                                                        const float* __restrict__ w,
                                                        const float* __restrict__ b,
                                                        float* __restrict__ out, int M) {
  int gw = (blockIdx.x * blockDim.x + threadIdx.x) >> 6;
  int lane = threadIdx.x & 63;
  if (gw >= M) return;
  const float* hr = h + (size_t)gw * 128;
  float s = hr[lane] * w[lane] + hr[lane + 64] * w[lane + 64];
  #pragma unroll
  for (int off = 32; off; off >>= 1) s += __shfl_down(s, off, 64);
  if (lane == 0) out[gw] = s + b[0];
}

extern "C" void kernel_launch(void* const* d_in, const int* in_sizes, int n_in,
                              void* d_out, int out_size, void* d_ws, size_t ws_size,
                              hipStream_t stream) {
  const float* x  = (const float*)d_in[0];
  const int*   ei = (const int*)d_in[2];
  const float* W1 = (const float*)d_in[3];
  const float* b1 = (const float*)d_in[4];
  const float* W2 = (const float*)d_in[5];
  const float* b2 = (const float*)d_in[6];
  const float* W3 = (const float*)d_in[7];
  const float* b3 = (const float*)d_in[8];
  const float* W4 = (const float*)d_in[9];
  const float* b4 = (const float*)d_in[10];
  const float* W5 = (const float*)d_in[11];
  const float* b5 = (const float*)d_in[12];
  float* out = (float*)d_out;

  const int M = in_sizes[0] / 128;  // 50000
  const int E = in_sizes[2] / 2;    // 800000
  const int* src = ei;
  const int* dst = ei + E;

  // ---- workspace layout (16B-aligned sections first) ----
  unsigned short* w1h = (unsigned short*)d_ws;        // 128*256
  unsigned short* w1l = w1h + 128 * 256;
  unsigned short* w2h = w1l + 128 * 256;              // 256*256
  unsigned short* w2l = w2h + 256 * 256;
  unsigned short* w3h = w2l + 256 * 256;              // 256*256
  unsigned short* w3l = w3h + 256 * 256;
  unsigned short* w4h = w3l + 256 * 256;              // 256*128
  unsigned short* w4l = w4h + 256 * 128;
  float* B0 = (float*)(w4l + 256 * 128);              // M*256 f32
  float* B1 = B0 + (size_t)M * 256;                   // M*256 f32
  int* off    = (int*)(B1 + (size_t)M * 256);         // M+1
  int* cursor = off + (M + 1);                        // M
  int* csr    = cursor + M;                           // E

  dim3 blk(256);

  // ---- weight prep (independent, run first) ----
  prep_w<<<dim3(128 / 32, 256 / 64), blk, 0, stream>>>(W1, w1h, w1l, 128, 256);
  prep_w<<<dim3(256 / 32, 256 / 64), blk, 0, stream>>>(W2, w2h, w2l, 256, 256);
  prep_w<<<dim3(256 / 32, 256 / 64), blk, 0, stream>>>(W3, w3h, w3l, 256, 256);
  prep_w<<<dim3(256 / 32, 128 / 64), blk, 0, stream>>>(W4, w4h, w4l, 256, 128);

  // ---- CSR build ----
  zero_int_kernel<<<(M + 255) / 256, blk, 0, stream>>>(cursor, M);
  hist_kernel<<<(E + 255) / 256, blk, 0, stream>>>(dst, cursor, E);
  scan_kernel<<<1, 1024, 0, stream>>>(cursor, off, M);
  fill_kernel<<<(E + 255) / 256, blk, 0, stream>>>(src, dst, cursor, csr, E);

  const int MB = (M + 127) / 128;  // 391

  // ---- layer 1 ----
  gather_agg<32><<<(M + 7) / 8, blk, 0, stream>>>(x, off, csr, B0, M);
  gemm_mfma<<<dim3(MB, 2), blk, 0, stream>>>(B0, w1h, w1l, b1, B1, M, 256, 128);
  gemm_mfma<<<dim3(MB, 2), blk, 0, stream>>>(B1, w2h, w2l, b2, B0, M, 256, 256);
  // ---- layer 2 ----
  gather_agg<64><<<(M + 3) / 4, blk, 0, stream>>>(B0, off, csr, B1, M);
  gemm_mfma<<<dim3(MB, 2), blk, 0, stream>>>(B1, w3h, w3l, b3, B0, M, 256, 256);
  gemm_mfma<<<dim3(MB, 1), blk, 0, stream>>>(B0, w4h, w4l, b4, B1, M, 128, 256);
  // ---- final linear ----
  final_dot_kernel<<<(M + 3) / 4, blk, 0, stream>>>(B1, W5, b5, out, M);
}

// Round 4
// 438.739 us; speedup vs baseline: 9.9920x; 1.2562x over previous
//
#include <hip/hip_runtime.h>

#define ALPHA 0.2f

typedef __attribute__((ext_vector_type(8))) short bf16x8;
typedef __attribute__((ext_vector_type(4))) float f32x4;

static __device__ __forceinline__ float leaky_f(float v) {
  return v >= 0.0f ? v : ALPHA * v;
}

static __device__ __forceinline__ unsigned short f2bf(float f) {
  unsigned u = __float_as_uint(f);
  unsigned r = (u + 0x7FFFu + ((u >> 16) & 1u)) >> 16;
  return (unsigned short)r;
}
static __device__ __forceinline__ float bf2f(unsigned short h) {
  return __uint_as_float(((unsigned)h) << 16);
}

// ---------- CSR build ----------

__global__ __launch_bounds__(256) void zero_int_kernel(int* __restrict__ p, int n) {
  int i = blockIdx.x * blockDim.x + threadIdx.x;
  if (i < n) p[i] = 0;
}

__global__ __launch_bounds__(256) void hist_kernel(const int* __restrict__ dst,
                                                   int* __restrict__ cnt, int E) {
  int e = blockIdx.x * blockDim.x + threadIdx.x;
  if (e < E) atomicAdd(&cnt[dst[e]], 1);
}

// per-block sums of deg
__global__ __launch_bounds__(256) void blocksum_kernel(const int* __restrict__ deg,
                                                       int* __restrict__ blksum, int n) {
  __shared__ int red[4];
  int i = blockIdx.x * 256 + threadIdx.x;
  int v = (i < n) ? deg[i] : 0;
  #pragma unroll
  for (int off = 32; off; off >>= 1) v += __shfl_down(v, off, 64);
  int wv = threadIdx.x >> 6, ln = threadIdx.x & 63;
  if (ln == 0) red[wv] = v;
  __syncthreads();
  if (threadIdx.x == 0) blksum[blockIdx.x] = red[0] + red[1] + red[2] + red[3];
}

// single block: exclusive scan of blksum (nb <= 1024); writes off[n]=total
__global__ __launch_bounds__(1024) void scanblk_kernel(int* __restrict__ blksum,
                                                       int* __restrict__ off, int nb, int n) {
  __shared__ int s[1024];
  int t = threadIdx.x;
  int v = (t < nb) ? blksum[t] : 0;
  s[t] = v;
  __syncthreads();
  for (int d = 1; d < 1024; d <<= 1) {
    int u = (t >= d) ? s[t - d] : 0;
    __syncthreads();
    s[t] += u;
    __syncthreads();
  }
  if (t < nb) blksum[t] = s[t] - v;   // exclusive
  if (t == 0) off[n] = s[1023];       // total (padded zeros)
}

// block-local exclusive scan + base; writes off[] and cursor[]
__global__ __launch_bounds__(256) void scatteroff_kernel(const int* __restrict__ blkoff,
                                                         int* __restrict__ off,
                                                         int* __restrict__ cursor, int n) {
  __shared__ int s[256];
  int i = blockIdx.x * 256 + threadIdx.x;
  int v = (i < n) ? cursor[i] : 0;
  s[threadIdx.x] = v;
  __syncthreads();
  for (int d = 1; d < 256; d <<= 1) {
    int u = (threadIdx.x >= d) ? s[threadIdx.x - d] : 0;
    __syncthreads();
    s[threadIdx.x] += u;
    __syncthreads();
  }
  int excl = s[threadIdx.x] - v + blkoff[blockIdx.x];
  if (i < n) {
    off[i] = excl;
    cursor[i] = excl;
  }
}

__global__ __launch_bounds__(256) void fill_kernel(const int* __restrict__ src,
                                                   const int* __restrict__ dst,
                                                   int* __restrict__ cursor,
                                                   int* __restrict__ csr, int E) {
  int e = blockIdx.x * blockDim.x + threadIdx.x;
  if (e < E) {
    int p = atomicAdd(&cursor[dst[e]], 1);
    csr[p] = src[e];
  }
}

// ---------- aggregation: agg[i] = x[i] + sum_{p} x[csr[p]], 4-deep MLP ----------
template <int F4>
__global__ __launch_bounds__(256) void gather_agg(const float* __restrict__ x,
                                                  const int* __restrict__ off,
                                                  const int* __restrict__ csr,
                                                  float* __restrict__ agg, int M) {
  constexpr int GP = 256 / F4;
  int g = threadIdx.x / F4;
  int lane = threadIdx.x % F4;
  int node = blockIdx.x * GP + g;
  if (node >= M) return;
  const float4* xv = reinterpret_cast<const float4*>(x);
  float4 a0 = xv[(size_t)node * F4 + lane];
  float4 a1 = make_float4(0.f, 0.f, 0.f, 0.f);
  float4 a2 = make_float4(0.f, 0.f, 0.f, 0.f);
  float4 a3 = make_float4(0.f, 0.f, 0.f, 0.f);
  int p = off[node], p1 = off[node + 1];
  for (; p + 4 <= p1; p += 4) {
    int s0 = csr[p], s1 = csr[p + 1], s2 = csr[p + 2], s3 = csr[p + 3];
    float4 v0 = xv[(size_t)s0 * F4 + lane];
    float4 v1 = xv[(size_t)s1 * F4 + lane];
    float4 v2 = xv[(size_t)s2 * F4 + lane];
    float4 v3 = xv[(size_t)s3 * F4 + lane];
    a0.x += v0.x; a0.y += v0.y; a0.z += v0.z; a0.w += v0.w;
    a1.x += v1.x; a1.y += v1.y; a1.z += v1.z; a1.w += v1.w;
    a2.x += v2.x; a2.y += v2.y; a2.z += v2.z; a2.w += v2.w;
    a3.x += v3.x; a3.y += v3.y; a3.z += v3.z; a3.w += v3.w;
  }
  for (; p < p1; ++p) {
    int s = csr[p];
    float4 v = xv[(size_t)s * F4 + lane];
    a0.x += v.x; a0.y += v.y; a0.z += v.z; a0.w += v.w;
  }
  float4 acc;
  acc.x = (a0.x + a1.x) + (a2.x + a3.x);
  acc.y = (a0.y + a1.y) + (a2.y + a3.y);
  acc.z = (a0.z + a1.z) + (a2.z + a3.z);
  acc.w = (a0.w + a1.w) + (a2.w + a3.w);
  reinterpret_cast<float4*>(agg)[(size_t)node * F4 + lane] = acc;
}

// ---------- weight prep: W [K][N] f32 -> Wh, Wl [N][K] bf16 (hi/lo split) ----------
__global__ __launch_bounds__(256) void prep_w(const float* __restrict__ W,
                                              unsigned short* __restrict__ Wh,
                                              unsigned short* __restrict__ Wl,
                                              int K, int N) {
  __shared__ float T[32][65];
  int k0 = blockIdx.x * 32, n0 = blockIdx.y * 64;
  int t = threadIdx.x;
  int nn = t & 63, kk0 = t >> 6;
  #pragma unroll
  for (int i = 0; i < 8; ++i) {
    int kk = kk0 + i * 4;
    T[kk][nn] = W[(size_t)(k0 + kk) * N + n0 + nn];
  }
  __syncthreads();
  int kk = t & 31, nb = t >> 5;
  #pragma unroll
  for (int i = 0; i < 8; ++i) {
    int n2 = nb + i * 8;
    float f = T[kk][n2];
    unsigned short h = f2bf(f);
    float r = f - bf2f(h);
    Wh[(size_t)(n0 + n2) * K + k0 + kk] = h;
    Wl[(size_t)(n0 + n2) * K + k0 + kk] = f2bf(r);
  }
}

// ---------- GEMM: C = leaky(A @ W + bias) via 3-product bf16-split MFMA ----------
// FUSE=1: additionally out[row] = sum_col leaky(...)*w5[col] + b5 (requires N==128, gridDim.y==1)
template <int FUSE>
__global__ __launch_bounds__(256, 3) void gemm_mfma(const float* __restrict__ A,
                                                    const unsigned short* __restrict__ Bh,
                                                    const unsigned short* __restrict__ Bl,
                                                    const float* __restrict__ bias,
                                                    float* __restrict__ C,
                                                    int M, int N, int K,
                                                    const float* __restrict__ w5,
                                                    const float* __restrict__ b5p,
                                                    float* __restrict__ out) {
  __shared__ unsigned short Ah_s[128 * 32];
  __shared__ unsigned short Al_s[128 * 32];
  __shared__ unsigned short Bh_s[128 * 32];
  __shared__ unsigned short Bl_s[128 * 32];
  __shared__ float part_s[128][2];

  const int tid = threadIdx.x;
  const int bm = blockIdx.x * 128, bn = blockIdx.y * 128;
  const int lane = tid & 63;
  const int wave = tid >> 6;
  const int wr = (wave >> 1) * 64;
  const int wc = (wave & 1) * 64;

  f32x4 acc[4][4];
  #pragma unroll
  for (int mi = 0; mi < 4; ++mi)
    #pragma unroll
    for (int ni = 0; ni < 4; ++ni)
      acc[mi][ni] = (f32x4){0.f, 0.f, 0.f, 0.f};

  const int lrow = lane & 15;
  const int lslot = lane >> 4;

  for (int k0 = 0; k0 < K; k0 += 32) {
    #pragma unroll
    for (int h = 0; h < 2; ++h) {
      int p = tid + h * 256;
      int row = p >> 2, slot = p & 3;
      const float4* srcp =
          reinterpret_cast<const float4*>(A + (size_t)(bm + row) * K + k0 + slot * 8);
      float4 v0 = srcp[0], v1 = srcp[1];
      float vs[8] = {v0.x, v0.y, v0.z, v0.w, v1.x, v1.y, v1.z, v1.w};
      uint4 uh, ul;
      unsigned uhw[4], ulw[4];
      #pragma unroll
      for (int q = 0; q < 4; ++q) {
        unsigned short h0 = f2bf(vs[2 * q]);
        unsigned short h1 = f2bf(vs[2 * q + 1]);
        unsigned short l0 = f2bf(vs[2 * q] - bf2f(h0));
        unsigned short l1 = f2bf(vs[2 * q + 1] - bf2f(h1));
        uhw[q] = (unsigned)h0 | ((unsigned)h1 << 16);
        ulw[q] = (unsigned)l0 | ((unsigned)l1 << 16);
      }
      uh.x = uhw[0]; uh.y = uhw[1]; uh.z = uhw[2]; uh.w = uhw[3];
      ul.x = ulw[0]; ul.y = ulw[1]; ul.z = ulw[2]; ul.w = ulw[3];
      int dst = row * 32 + ((slot ^ ((row >> 1) & 3)) << 3);
      *reinterpret_cast<uint4*>(&Ah_s[dst]) = uh;
      *reinterpret_cast<uint4*>(&Al_s[dst]) = ul;
    }
    #pragma unroll
    for (int h = 0; h < 2; ++h) {
      int p = tid + h * 256;
      int row = p >> 2, slot = p & 3;
      int dst = row * 32 + ((slot ^ ((row >> 1) & 3)) << 3);
      uint4 vh = *reinterpret_cast<const uint4*>(Bh + (size_t)(bn + row) * K + k0 + slot * 8);
      uint4 vl = *reinterpret_cast<const uint4*>(Bl + (size_t)(bn + row) * K + k0 + slot * 8);
      *reinterpret_cast<uint4*>(&Bh_s[dst]) = vh;
      *reinterpret_cast<uint4*>(&Bl_s[dst]) = vl;
    }
    __syncthreads();

    bf16x8 ah[4], al[4], bh[4], bl[4];
    #pragma unroll
    for (int mi = 0; mi < 4; ++mi) {
      int r = wr + mi * 16 + lrow;
      int off = r * 32 + (((lslot ^ ((r >> 1) & 3))) << 3);
      ah[mi] = *reinterpret_cast<const bf16x8*>(&Ah_s[off]);
      al[mi] = *reinterpret_cast<const bf16x8*>(&Al_s[off]);
    }
    #pragma unroll
    for (int ni = 0; ni < 4; ++ni) {
      int r = wc + ni * 16 + lrow;
      int off = r * 32 + (((lslot ^ ((r >> 1) & 3))) << 3);
      bh[ni] = *reinterpret_cast<const bf16x8*>(&Bh_s[off]);
      bl[ni] = *reinterpret_cast<const bf16x8*>(&Bl_s[off]);
    }
    #pragma unroll
    for (int mi = 0; mi < 4; ++mi)
      #pragma unroll
      for (int ni = 0; ni < 4; ++ni) {
        acc[mi][ni] = __builtin_amdgcn_mfma_f32_16x16x32_bf16(ah[mi], bh[ni], acc[mi][ni], 0, 0, 0);
        acc[mi][ni] = __builtin_amdgcn_mfma_f32_16x16x32_bf16(ah[mi], bl[ni], acc[mi][ni], 0, 0, 0);
        acc[mi][ni] = __builtin_amdgcn_mfma_f32_16x16x32_bf16(al[mi], bh[ni], acc[mi][ni], 0, 0, 0);
      }
    __syncthreads();
  }

  if (FUSE) {
    // fused: out[row] = sum_col leaky(acc+bias)*w5[col] + b5
    float w5v[4], bv[4];
    #pragma unroll
    for (int ni = 0; ni < 4; ++ni) {
      int col = wc + ni * 16 + lrow;
      w5v[ni] = w5[col];
      bv[ni] = bias[col];
    }
    #pragma unroll
    for (int mi = 0; mi < 4; ++mi) {
      #pragma unroll
      for (int j = 0; j < 4; ++j) {
        float s = 0.f;
        #pragma unroll
        for (int ni = 0; ni < 4; ++ni)
          s += leaky_f(acc[mi][ni][j] + bv[ni]) * w5v[ni];
        s += __shfl_xor(s, 1, 64);
        s += __shfl_xor(s, 2, 64);
        s += __shfl_xor(s, 4, 64);
        s += __shfl_xor(s, 8, 64);
        if (lrow == 0) part_s[wr + mi * 16 + lslot * 4 + j][wave & 1] = s;
      }
    }
    __syncthreads();
    if (tid < 128) {
      int row = bm + tid;
      if (row < M) out[row] = part_s[tid][0] + part_s[tid][1] + b5p[0];
    }
  } else {
    #pragma unroll
    for (int ni = 0; ni < 4; ++ni) {
      int col = bn + wc + ni * 16 + lrow;
      float bv = bias[col];
      #pragma unroll
      for (int mi = 0; mi < 4; ++mi) {
        int rbase = bm + wr + mi * 16 + lslot * 4;
        #pragma unroll
        for (int j = 0; j < 4; ++j) {
          int row = rbase + j;
          if (row < M) C[(size_t)row * N + col] = leaky_f(acc[mi][ni][j] + bv);
        }
      }
    }
  }
}

extern "C" void kernel_launch(void* const* d_in, const int* in_sizes, int n_in,
                              void* d_out, int out_size, void* d_ws, size_t ws_size,
                              hipStream_t stream) {
  const float* x  = (const float*)d_in[0];
  const int*   ei = (const int*)d_in[2];
  const float* W1 = (const float*)d_in[3];
  const float* b1 = (const float*)d_in[4];
  const float* W2 = (const float*)d_in[5];
  const float* b2 = (const float*)d_in[6];
  const float* W3 = (const float*)d_in[7];
  const float* b3 = (const float*)d_in[8];
  const float* W4 = (const float*)d_in[9];
  const float* b4 = (const float*)d_in[10];
  const float* W5 = (const float*)d_in[11];
  const float* b5 = (const float*)d_in[12];
  float* out = (float*)d_out;

  const int M = in_sizes[0] / 128;  // 50000
  const int E = in_sizes[2] / 2;    // 800000
  const int* src = ei;
  const int* dst = ei + E;

  // ---- workspace layout ----
  unsigned short* w1h = (unsigned short*)d_ws;        // 128*256
  unsigned short* w1l = w1h + 128 * 256;
  unsigned short* w2h = w1l + 128 * 256;              // 256*256
  unsigned short* w2l = w2h + 256 * 256;
  unsigned short* w3h = w2l + 256 * 256;              // 256*256
  unsigned short* w3l = w3h + 256 * 256;
  unsigned short* w4h = w3l + 256 * 256;              // 256*128
  unsigned short* w4l = w4h + 256 * 128;
  float* B0 = (float*)(w4l + 256 * 128);              // M*256 f32
  float* B1 = B0 + (size_t)M * 256;                   // M*256 f32
  int* off    = (int*)(B1 + (size_t)M * 256);         // M+1
  int* cursor = off + (M + 1);                        // M
  int* csr    = cursor + M;                           // E
  int* blksum = csr + E;                              // ~196

  dim3 blk(256);
  const int NB = (M + 255) / 256;

  // ---- weight prep ----
  prep_w<<<dim3(128 / 32, 256 / 64), blk, 0, stream>>>(W1, w1h, w1l, 128, 256);
  prep_w<<<dim3(256 / 32, 256 / 64), blk, 0, stream>>>(W2, w2h, w2l, 256, 256);
  prep_w<<<dim3(256 / 32, 256 / 64), blk, 0, stream>>>(W3, w3h, w3l, 256, 256);
  prep_w<<<dim3(256 / 32, 128 / 64), blk, 0, stream>>>(W4, w4h, w4l, 256, 128);

  // ---- CSR build ----
  zero_int_kernel<<<NB, blk, 0, stream>>>(cursor, M);
  hist_kernel<<<(E + 255) / 256, blk, 0, stream>>>(dst, cursor, E);
  blocksum_kernel<<<NB, blk, 0, stream>>>(cursor, blksum, M);
  scanblk_kernel<<<1, 1024, 0, stream>>>(blksum, off, NB, M);
  scatteroff_kernel<<<NB, blk, 0, stream>>>(blksum, off, cursor, M);
  fill_kernel<<<(E + 255) / 256, blk, 0, stream>>>(src, dst, cursor, csr, E);

  const int MB = (M + 127) / 128;  // 391

  // ---- layer 1 ----
  gather_agg<32><<<(M + 7) / 8, blk, 0, stream>>>(x, off, csr, B0, M);
  gemm_mfma<0><<<dim3(MB, 2), blk, 0, stream>>>(B0, w1h, w1l, b1, B1, M, 256, 128,
                                                nullptr, nullptr, nullptr);
  gemm_mfma<0><<<dim3(MB, 2), blk, 0, stream>>>(B1, w2h, w2l, b2, B0, M, 256, 256,
                                                nullptr, nullptr, nullptr);
  // ---- layer 2 ----
  gather_agg<64><<<(M + 3) / 4, blk, 0, stream>>>(B0, off, csr, B1, M);
  gemm_mfma<0><<<dim3(MB, 2), blk, 0, stream>>>(B1, w3h, w3l, b3, B0, M, 256, 256,
                                                nullptr, nullptr, nullptr);
  // ---- layer 2 second MLP + fused final linear ----
  gemm_mfma<1><<<dim3(MB, 1), blk, 0, stream>>>(B0, w4h, w4l, b4, nullptr, M, 128, 256,
                                                W5, b5, out);
}